// Round 2
// baseline (146.732 us; speedup 1.0000x reference)
//
#include <hip/hip_runtime.h>
#include <hip/hip_bf16.h>

#define B 16
#define K 256
#define Z 128
#define H 128
#define R 8   // rows per block in the linear kernels

// ---------------- Kernel A: m1z = z@W1^T+b1, m2z = z@W2^T+b2 ----------------
// one block per R rows, 128 threads = output channel o
__global__ __launch_bounds__(128) void k_lin(
    const float* __restrict__ z,
    const float* __restrict__ W1, const float* __restrict__ b1,
    const float* __restrict__ W2, const float* __restrict__ b2,
    float* __restrict__ m1z, float* __restrict__ m2z)
{
    const int row0 = blockIdx.x * R;
    const int t = threadIdx.x;          // output channel
    __shared__ float zs[R][Z];
#pragma unroll
    for (int r = 0; r < R; ++r) zs[r][t] = z[(row0 + r) * Z + t];
    __syncthreads();

    float a1[R], a2[R];
    const float bb1 = b1[t], bb2 = b2[t];
#pragma unroll
    for (int r = 0; r < R; ++r) { a1[r] = bb1; a2[r] = bb2; }

    const float* w1r = W1 + t * Z;
    const float* w2r = W2 + t * Z;
#pragma unroll
    for (int d = 0; d < Z; d += 4) {
        const float4 u1 = *(const float4*)(w1r + d);
        const float4 u2 = *(const float4*)(w2r + d);
#pragma unroll
        for (int r = 0; r < R; ++r) {
            const float4 zv = *(const float4*)&zs[r][d];
            a1[r] += zv.x * u1.x + zv.y * u1.y + zv.z * u1.z + zv.w * u1.w;
            a2[r] += zv.x * u2.x + zv.y * u2.y + zv.z * u2.z + zv.w * u2.w;
        }
    }
#pragma unroll
    for (int r = 0; r < R; ++r) {
        m1z[(row0 + r) * Z + t] = a1[r];
        m2z[(row0 + r) * Z + t] = a2[r];
    }
}

// ---------------- Kernel B: m[b,i,:] = relu(m1z[b,i,:] + max_{j:P[b,j,i]!=0} m2z[b,j,:])
// one block per (b,i), 128 threads = feature d. Mask column staged in LDS,
// per-j branch is block-uniform -> inactive j's loads are skipped.
__global__ __launch_bounds__(128) void k_max(
    const int* __restrict__ P, const float* __restrict__ m1z,
    const float* __restrict__ m2z, float* __restrict__ m)
{
    const int b = blockIdx.x >> 8;      // / K
    const int i = blockIdx.x & (K - 1);
    const int d = threadIdx.x;

    __shared__ int mask[K];
    const int* Pcol = P + b * K * K + i;      // P[b, j, i], stride K over j
    mask[d]       = Pcol[d * K];
    mask[d + 128] = Pcol[(d + 128) * K];
    __syncthreads();

    const float* m2b = m2z + b * K * Z + d;
    float acc = -3.4e38f;
    for (int j = 0; j < K; ++j) {
        if (mask[j]) acc = fmaxf(acc, m2b[j * Z]);
    }
    const int idx = blockIdx.x * Z + d;
    m[idx] = fmaxf(m1z[idx] + acc, 0.0f);
}

// ---------------- Kernel C: out = relu(concat(z, m) @ Wu^T + bu) -------------
// one block per R rows, 128 threads = output h
__global__ __launch_bounds__(128) void k_out(
    const float* __restrict__ z, const float* __restrict__ m,
    const float* __restrict__ Wu, const float* __restrict__ bu,
    float* __restrict__ out)
{
    const int row0 = blockIdx.x * R;
    const int t = threadIdx.x;          // output channel h
    __shared__ float xs[R][2 * Z];
#pragma unroll
    for (int r = 0; r < R; ++r) {
        xs[r][t]     = z[(row0 + r) * Z + t];
        xs[r][Z + t] = m[(row0 + r) * Z + t];
    }
    __syncthreads();

    float acc[R];
    const float bb = bu[t];
#pragma unroll
    for (int r = 0; r < R; ++r) acc[r] = bb;

    const float* wr = Wu + t * (2 * Z);
#pragma unroll
    for (int d = 0; d < 2 * Z; d += 4) {
        const float4 u = *(const float4*)(wr + d);
#pragma unroll
        for (int r = 0; r < R; ++r) {
            const float4 xv = *(const float4*)&xs[r][d];
            acc[r] += xv.x * u.x + xv.y * u.y + xv.z * u.z + xv.w * u.w;
        }
    }
#pragma unroll
    for (int r = 0; r < R; ++r)
        out[(row0 + r) * H + t] = fmaxf(acc[r], 0.0f);
}

extern "C" void kernel_launch(void* const* d_in, const int* in_sizes, int n_in,
                              void* d_out, int out_size, void* d_ws, size_t ws_size,
                              hipStream_t stream) {
    const float* z  = (const float*)d_in[0];
    const int*   P  = (const int*)d_in[1];
    const float* W1 = (const float*)d_in[2];
    const float* b1 = (const float*)d_in[3];
    const float* W2 = (const float*)d_in[4];
    const float* b2 = (const float*)d_in[5];
    const float* Wu = (const float*)d_in[6];
    const float* bu = (const float*)d_in[7];

    float* m1z = (float*)d_ws;             // [B*K*Z] f32
    float* m2z = m1z + B * K * Z;          // [B*K*Z] f32
    float* mm  = m2z + B * K * Z;          // [B*K*Z] f32

    k_lin<<<(B * K) / R, 128, 0, stream>>>(z, W1, b1, W2, b2, m1z, m2z);
    k_max<<<B * K, 128, 0, stream>>>(P, m1z, m2z, mm);
    k_out<<<(B * K) / R, 128, 0, stream>>>(z, mm, Wu, bu, (float*)d_out);
}

// Round 3
// 119.588 us; speedup vs baseline: 1.2270x; 1.2270x over previous
//
#include <hip/hip_runtime.h>
#include <hip/hip_bf16.h>
#include <math.h>

#define B 16
#define K 256
#define Z 128
#define H 128

// ---------------- Kernel A: m1z = z@W1^T+b1, m2z = z@W2^T+b2 ----------------
// block = 256 threads = (o: 128 outputs) x (rh: 2 row-groups of 4 rows); 8 rows/block
__global__ __launch_bounds__(256) void k_lin(
    const float* __restrict__ z,
    const float* __restrict__ W1, const float* __restrict__ b1,
    const float* __restrict__ W2, const float* __restrict__ b2,
    float* __restrict__ m1z, float* __restrict__ m2z)
{
    const int tid  = threadIdx.x;
    const int o    = tid & 127;
    const int rh   = tid >> 7;            // 0,1
    const int row0 = blockIdx.x * 8;

    __shared__ float zs[8][Z];
    {   // 8 rows x 128 = 1024 floats; 256 threads x 1 float4
        const int rr = tid >> 5;          // 0..7
        const int cc = (tid & 31) * 4;    // 0..124
        *(float4*)&zs[rr][cc] = *(const float4*)&z[(row0 + rr) * Z + cc];
    }
    __syncthreads();

    float a1[4], a2[4];
    const float bb1 = b1[o], bb2 = b2[o];
#pragma unroll
    for (int r = 0; r < 4; ++r) { a1[r] = bb1; a2[r] = bb2; }

    const float* w1r = W1 + o * Z;
    const float* w2r = W2 + o * Z;
#pragma unroll
    for (int d = 0; d < Z; d += 4) {
        const float4 u1 = *(const float4*)(w1r + d);
        const float4 u2 = *(const float4*)(w2r + d);
#pragma unroll
        for (int r = 0; r < 4; ++r) {
            const float4 zv = *(const float4*)&zs[rh * 4 + r][d];  // LDS broadcast
            a1[r] += zv.x * u1.x + zv.y * u1.y + zv.z * u1.z + zv.w * u1.w;
            a2[r] += zv.x * u2.x + zv.y * u2.y + zv.z * u2.z + zv.w * u2.w;
        }
    }
#pragma unroll
    for (int r = 0; r < 4; ++r) {
        const int row = row0 + rh * 4 + r;
        m1z[row * Z + o] = a1[r];
        m2z[row * Z + o] = a2[r];
    }
}

// ---------------- Kernel B: tropical GEMM  m[i,d] = relu(m1z[i,d] + max_j (m2z[j,d] + F[i,j]))
// grid (b, dh, it): 16 x 2 x 16.  Block 256 = 4 waves; wave w owns 4 i's; lane = d (64).
// LDS: sv = m2z j-tile [128][64] (32 KB, 2 passes), smask = F [16][257] floats (16 KB).
__global__ __launch_bounds__(256) void k_max(
    const int* __restrict__ P, const float* __restrict__ m1z,
    const float* __restrict__ m2z, float* __restrict__ m)
{
    const int b  = blockIdx.x;
    const int d0 = blockIdx.y * 64;
    const int i0 = blockIdx.z * 16;
    const int tid  = threadIdx.x;
    const int lane = tid & 63;            // d within half
    const int wave = tid >> 6;            // 0..3

    __shared__ float sv[128][64];
    __shared__ float smask[16][257];

    {   // stage mask column-block as 0 / -inf floats
        const int ii = tid & 15;
        const int jg = tid >> 4;          // 0..15
#pragma unroll
        for (int g = 0; g < 16; ++g) {
            const int j = jg + 16 * g;
            const int pv = P[(b * K + j) * K + i0 + ii];
            smask[ii][j] = pv ? 0.0f : -INFINITY;
        }
    }

    float acc[4];
#pragma unroll
    for (int k = 0; k < 4; ++k) acc[k] = -INFINITY;

    for (int pass = 0; pass < 2; ++pass) {
        __syncthreads();                  // protect sv before overwrite
        {   // stage 128 j-rows x 64 d of m2z
            const int c4 = (tid & 15) * 4;
#pragma unroll
            for (int s = 0; s < 8; ++s) {
                const int jj = (tid >> 4) + 16 * s;
                *(float4*)&sv[jj][c4] =
                    *(const float4*)&m2z[(b * K + pass * 128 + jj) * Z + d0 + c4];
            }
        }
        __syncthreads();

        const int jbase = pass * 128;
        for (int jj = 0; jj < 128; ++jj) {
            const float val = sv[jj][lane];
            const int j = jbase + jj;
#pragma unroll
            for (int k = 0; k < 4; ++k) {
                const float fm = smask[wave * 4 + k][j];   // broadcast read
                acc[k] = fmaxf(acc[k], val + fm);
            }
        }
    }

#pragma unroll
    for (int k = 0; k < 4; ++k) {
        const int i = i0 + wave * 4 + k;
        const int idx = (b * K + i) * Z + d0 + lane;
        m[idx] = fmaxf(m1z[idx] + acc[k], 0.0f);
    }
}

// ---------------- Kernel C: out = relu(concat(z, m) @ Wu^T + bu) -------------
// block = 256 threads = (h: 128) x (rh: 2 row-groups of 4); 8 rows/block
__global__ __launch_bounds__(256) void k_out(
    const float* __restrict__ z, const float* __restrict__ mm,
    const float* __restrict__ Wu, const float* __restrict__ bu,
    float* __restrict__ out)
{
    const int tid  = threadIdx.x;
    const int o    = tid & 127;
    const int rh   = tid >> 7;
    const int row0 = blockIdx.x * 8;

    __shared__ float xs[8][2 * Z];
    {   // 8 rows x 256 floats
        const int rr = tid >> 5;          // 0..7
        const int cc = (tid & 31) * 4;
        *(float4*)&xs[rr][cc]       = *(const float4*)&z [(row0 + rr) * Z + cc];
        *(float4*)&xs[rr][Z + cc]   = *(const float4*)&mm[(row0 + rr) * Z + cc];
    }
    __syncthreads();

    float acc[4];
    const float bb = bu[o];
#pragma unroll
    for (int r = 0; r < 4; ++r) acc[r] = bb;

    const float* wr = Wu + o * (2 * Z);
#pragma unroll
    for (int d = 0; d < 2 * Z; d += 4) {
        const float4 u = *(const float4*)(wr + d);
#pragma unroll
        for (int r = 0; r < 4; ++r) {
            const float4 xv = *(const float4*)&xs[rh * 4 + r][d];  // broadcast
            acc[r] += xv.x * u.x + xv.y * u.y + xv.z * u.z + xv.w * u.w;
        }
    }
#pragma unroll
    for (int r = 0; r < 4; ++r)
        out[(row0 + rh * 4 + r) * H + o] = fmaxf(acc[r], 0.0f);
}

extern "C" void kernel_launch(void* const* d_in, const int* in_sizes, int n_in,
                              void* d_out, int out_size, void* d_ws, size_t ws_size,
                              hipStream_t stream) {
    const float* z  = (const float*)d_in[0];
    const int*   P  = (const int*)d_in[1];
    const float* W1 = (const float*)d_in[2];
    const float* b1 = (const float*)d_in[3];
    const float* W2 = (const float*)d_in[4];
    const float* b2 = (const float*)d_in[5];
    const float* Wu = (const float*)d_in[6];
    const float* bu = (const float*)d_in[7];

    float* m1z = (float*)d_ws;             // [B*K*Z] f32
    float* m2z = m1z + B * K * Z;          // [B*K*Z] f32
    float* mm  = m2z + B * K * Z;          // [B*K*Z] f32

    k_lin<<<(B * K) / 8, 256, 0, stream>>>(z, W1, b1, W2, b2, m1z, m2z);
    k_max<<<dim3(B, 2, 16), 256, 0, stream>>>(P, m1z, m2z, mm);
    k_out<<<(B * K) / 8, 256, 0, stream>>>(z, mm, Wu, bu, (float*)d_out);
}

// Round 5
// 115.793 us; speedup vs baseline: 1.2672x; 1.0328x over previous
//
#include <hip/hip_runtime.h>
#include <math.h>

#define B 16
#define K 256
#define Z 128
#define H 128

typedef _Float16 h2 __attribute__((ext_vector_type(2)));
union U32H2 { unsigned int u; h2 h; };

// ---------------- Kernel A: m1z = z@W1^T+b1, m2z = z@W2^T+b2 ----------------
// block 256 thr = (o:128) x (rh:2 row-groups of 4); 8 rows/block; grid 512.
// Weights staged through LDS in 32-d chunks with coalesced float2 loads.
__global__ __launch_bounds__(256) void k_lin(
    const float* __restrict__ z,
    const float* __restrict__ W1, const float* __restrict__ b1,
    const float* __restrict__ W2, const float* __restrict__ b2,
    float* __restrict__ m1z, float* __restrict__ m2z)
{
    const int tid  = threadIdx.x;
    const int o    = tid & 127;
    const int rh   = tid >> 7;
    const int row0 = blockIdx.x * 8;

    __shared__ float zs[8][Z];        // 4 KB
    __shared__ float sw1[Z][34];      // 17.4 KB: chunk [o][32d] + pad2 (bank spread)
    __shared__ float sw2[Z][34];

    {   // coalesced z stage: 8 rows x 128
        const int rr = tid >> 5, cc = (tid & 31) * 4;
        *(float4*)&zs[rr][cc] = *(const float4*)&z[(row0 + rr) * Z + cc];
    }

    float a1[4], a2[4];
    const float bb1 = b1[o], bb2 = b2[o];
#pragma unroll
    for (int r = 0; r < 4; ++r) { a1[r] = bb1; a2[r] = bb2; }

    for (int kc = 0; kc < 4; ++kc) {
        __syncthreads();              // prev chunk consumed (and zs ready, kc=0)
        // stage W1/W2 chunk: 128 rows x 16 float2 each, lane-consecutive
#pragma unroll
        for (int q = 0; q < 8; ++q) {
            const int f  = q * 256 + tid;   // float2 idx in [0,2048)
            const int oo = f >> 4;
            const int jj = (f & 15) * 2;
            *(float2*)&sw1[oo][jj] = *(const float2*)&W1[oo * Z + kc * 32 + jj];
            *(float2*)&sw2[oo][jj] = *(const float2*)&W2[oo * Z + kc * 32 + jj];
        }
        __syncthreads();
#pragma unroll
        for (int j2 = 0; j2 < 16; ++j2) {
            const float2 w1 = *(const float2*)&sw1[o][j2 * 2];
            const float2 w2 = *(const float2*)&sw2[o][j2 * 2];
#pragma unroll
            for (int r = 0; r < 4; ++r) {
                const float2 zv = *(const float2*)&zs[rh * 4 + r][kc * 32 + j2 * 2];
                a1[r] += zv.x * w1.x + zv.y * w1.y;
                a2[r] += zv.x * w2.x + zv.y * w2.y;
            }
        }
    }
#pragma unroll
    for (int r = 0; r < 4; ++r) {
        const int row = row0 + rh * 4 + r;
        m1z[row * Z + o] = a1[r];
        m2z[row * Z + o] = a2[r];
    }
}

// ---------------- Kernel B (fused): tropical max + concat GEMM ---------------
// grid (b:16, itile:32); block 256 = 4 waves; block covers 8 i x 128 d x 256 j,
// then out[i, :] = relu(concat(z,m) @ Wu^T + bu) for its 8 rows.
// Tropical inner loop in packed f16 (v_pk_add_f16 / v_pk_max_f16): lane = d-pair.
__global__ __launch_bounds__(256) void k_maxout(
    const float* __restrict__ z, const int* __restrict__ P,
    const float* __restrict__ m1z, const float* __restrict__ m2z,
    const float* __restrict__ Wu, const float* __restrict__ bu,
    float* __restrict__ out)
{
    const int b    = blockIdx.x;
    const int i0   = blockIdx.y * 8;
    const int tid  = threadIdx.x;
    const int lane = tid & 63;        // d-pair: d = 2*lane, 2*lane+1
    const int wv   = tid >> 6;        // wave -> rows 2wv, 2wv+1

    __shared__ __align__(16) char pool[128 * 128 * 2];  // 32 KB: sv then swu
    __shared__ unsigned int smask[8][K];                // 8 KB: 0 or (-inf,-inf) f16 pair
    __shared__ float xs[8][264];                        // 8.4 KB: concat(z,m) rows (+pad)
    h2    (*sv)[64]  = (h2    (*)[64])pool;             // m2z j-tile, f16 pairs
    float (*swu)[34] = (float (*)[34])pool;             // Wu chunk

    {   // xs z-part (coalesced); read early to overlap
        const int rr = tid >> 5, cc = (tid & 31) * 4;
        *(float4*)&xs[rr][cc] = *(const float4*)&z[(b * K + i0 + rr) * Z + cc];
    }
    {   // mask stage: smask[ii][j] for 8 i x 256 j
        const int ii = tid & 7;
        const int jb = tid >> 3;      // 0..31
#pragma unroll
        for (int g = 0; g < 8; ++g) {
            const int j = jb + 32 * g;
            const int pv = P[(b * K + j) * K + i0 + ii];
            smask[ii][j] = pv ? 0u : 0xFC00FC00u;   // (-inf,-inf) in f16
        }
    }

    U32H2 ninf; ninf.u = 0xFC00FC00u;
    h2 acc0 = ninf.h, acc1 = ninf.h;

    for (int jt = 0; jt < 2; ++jt) {
        __syncthreads();              // prev tile consumed (jt=0: covers z/mask stage)
        // stage sv: m2z rows [jt*128, +128) as f16 pairs; coalesced float4 reads
#pragma unroll
        for (int q = 0; q < 16; ++q) {
            const int e  = q * 256 + tid;     // float4 idx in [0,4096)
            const int jj = e >> 5;
            const int c4 = e & 31;
            const float4 v = *(const float4*)&m2z[(b * K + jt * 128 + jj) * Z + c4 * 4];
            h2 p0; p0.x = (_Float16)v.x; p0.y = (_Float16)v.y;
            h2 p1; p1.x = (_Float16)v.z; p1.y = (_Float16)v.w;
            sv[jj][c4 * 2]     = p0;
            sv[jj][c4 * 2 + 1] = p1;
        }
        __syncthreads();

        const unsigned int* mr0 = &smask[2 * wv][jt * 128];
        const unsigned int* mr1 = &smask[2 * wv + 1][jt * 128];
        for (int jj = 0; jj < 128; ++jj) {
            const h2 v = sv[jj][lane];
            U32H2 f0, f1; f0.u = mr0[jj]; f1.u = mr1[jj];
            acc0 = __builtin_elementwise_max(acc0, v + f0.h);
            acc1 = __builtin_elementwise_max(acc1, v + f1.h);
        }
    }

    {   // m rows -> xs[:, 128..255] = relu(m1z + max)
        const int r0 = 2 * wv, r1 = 2 * wv + 1;
        const float2 ma = *(const float2*)&m1z[(b * K + i0 + r0) * Z + 2 * lane];
        const float2 mb = *(const float2*)&m1z[(b * K + i0 + r1) * Z + 2 * lane];
        xs[r0][Z + 2 * lane]     = fmaxf(ma.x + (float)acc0.x, 0.0f);
        xs[r0][Z + 2 * lane + 1] = fmaxf(ma.y + (float)acc0.y, 0.0f);
        xs[r1][Z + 2 * lane]     = fmaxf(mb.x + (float)acc1.x, 0.0f);
        xs[r1][Z + 2 * lane + 1] = fmaxf(mb.y + (float)acc1.y, 0.0f);
    }

    // ---- concat GEMM: out[row, o] = relu(sum_k xs[row][k] * Wu[o][k] + bu[o])
    const int o  = tid & 127;
    const int rh = tid >> 7;
    float acc[4];
    const float bb = bu[o];
#pragma unroll
    for (int r = 0; r < 4; ++r) acc[r] = bb;

    for (int kc = 0; kc < 8; ++kc) {
        __syncthreads();              // sv/xs writes done (kc=0), prev chunk consumed
#pragma unroll
        for (int q = 0; q < 8; ++q) { // stage Wu chunk [128][32], coalesced float2
            const int f  = q * 256 + tid;
            const int oo = f >> 4;
            const int jj = (f & 15) * 2;
            *(float2*)&swu[oo][jj] = *(const float2*)&Wu[oo * (2 * Z) + kc * 32 + jj];
        }
        __syncthreads();
#pragma unroll
        for (int j2 = 0; j2 < 16; ++j2) {
            const float2 w = *(const float2*)&swu[o][j2 * 2];
#pragma unroll
            for (int r = 0; r < 4; ++r) {
                const float2 xv = *(const float2*)&xs[rh * 4 + r][kc * 32 + j2 * 2];
                acc[r] += xv.x * w.x + xv.y * w.y;
            }
        }
    }
#pragma unroll
    for (int r = 0; r < 4; ++r)
        out[(b * K + i0 + rh * 4 + r) * H + o] = fmaxf(acc[r], 0.0f);
}

extern "C" void kernel_launch(void* const* d_in, const int* in_sizes, int n_in,
                              void* d_out, int out_size, void* d_ws, size_t ws_size,
                              hipStream_t stream) {
    const float* z  = (const float*)d_in[0];
    const int*   P  = (const int*)d_in[1];
    const float* W1 = (const float*)d_in[2];
    const float* b1 = (const float*)d_in[3];
    const float* W2 = (const float*)d_in[4];
    const float* b2 = (const float*)d_in[5];
    const float* Wu = (const float*)d_in[6];
    const float* bu = (const float*)d_in[7];

    float* m1z = (float*)d_ws;             // [B*K*Z] f32
    float* m2z = m1z + B * K * Z;          // [B*K*Z] f32

    k_lin<<<(B * K) / 8, 256, 0, stream>>>(z, W1, b1, W2, b2, m1z, m2z);
    k_maxout<<<dim3(B, K / 8), 256, 0, stream>>>(z, P, m1z, m2z, Wu, bu, (float*)d_out);
}